// Round 6
// baseline (623.155 us; speedup 1.0000x reference)
//
#include <hip/hip_runtime.h>

// MixingAttention on MI355X (gfx950) — ROUND 6.
// Root cause found: d_out is FLOAT32 (npz sizes prove it; rounds 1/2/5 wrote
// bf16 into it -> packed-word decorrelation -> the bit-identical 0.128 absmax).
// This build = round 5 with final GEMMs storing f32 to d_out.

using s16x8 = __attribute__((ext_vector_type(8))) short;   // 8 bf16
using f32x4 = __attribute__((ext_vector_type(4))) float;   // 4 f32 acc

#define NTOK 144
#define NHEADS 16
#define CDIM 512
#define TROWS 9216     // 64*144 template rows
#define SROWS 36864    // 256*144 search rows
#define TOTROWS 46080
#define CH_WIN 80
#define CH_ROWS (CH_WIN * NTOK)   // 11520
#define NCHUNK 4

__device__ __forceinline__ unsigned short f2bf(float f) {
  unsigned u = __float_as_uint(f);
  u += 0x7fffu + ((u >> 16) & 1u);     // RNE
  return (unsigned short)(u >> 16);
}
__device__ __forceinline__ float bf2f(unsigned short u) {
  return __uint_as_float(((unsigned)u) << 16);
}

// ---------------- prep kernels ----------------

// w: (Kd, Nd) f32 row-major  ->  wT: (Nd, Kd) bf16 row-major
__global__ void transpose_cast(const float* __restrict__ w,
                               unsigned short* __restrict__ wT, int Kd, int Nd) {
  int i = blockIdx.x * 256 + threadIdx.x;
  if (i >= Kd * Nd) return;
  int n = i / Kd, k = i % Kd;
  wT[i] = f2bf(w[(size_t)k * Nd + n]);
}

// biasExp[h][i][j] = rpb[((ih-jh+11)*23 + (iw-jw+11))*16 + h]
__global__ void expand_bias(const float* __restrict__ rpb, float* __restrict__ biasExp) {
  int i = blockIdx.x * 256 + threadIdx.x;
  if (i >= NHEADS * NTOK * NTOK) return;
  int h = i / (NTOK * NTOK);
  int rem = i % (NTOK * NTOK);
  int qi = rem / NTOK, kj = rem % NTOK;
  int dh = qi / 12 - kj / 12 + 11;
  int dw = qi % 12 - kj % 12 + 11;
  biasExp[i] = rpb[(dh * 23 + dw) * NHEADS + h];
}

// ---------------- generic 128x128 MFMA GEMM ----------------
// C(M,N) = A(M,K) @ B(K,N); B pre-transposed BT(N,K) bf16.
// AF32: A is f32 (cast to bf16 during staging) else bf16.
// EPI 0: +bias[col], store bf16.
// EPI 1: +bias[col], scale cols<512 by 32^-0.5 (Q), store bf16 (qkv).
// EPI 2: +bias[col], store FLOAT32 (final outputs -> d_out).
template<int AF32, int EPI>
__global__ __launch_bounds__(256) void gemm128(
    const void* __restrict__ Av, const unsigned short* __restrict__ BT,
    const float* __restrict__ bias, void* __restrict__ Cout,
    int M, int N, int K)
{
  constexpr int PK = 40;                 // 32+8 pad: <=2-way bank conflict (free)
  __shared__ short As[128 * PK];
  __shared__ short Bs[128 * PK];
  const int t = threadIdx.x;
  const int lane = t & 63, wv = t >> 6, lg = lane >> 4, lc = lane & 15;
  const int bm = blockIdx.x * 128, bn = blockIdx.y * 128;
  const int srow = t >> 1, sk = (t & 1) * 16;

  f32x4 acc[2][8] = {};
  const float* Af = (const float*)Av;
  const unsigned short* Ab = (const unsigned short*)Av;

  for (int kt = 0; kt < K; kt += 32) {
    __syncthreads();
    if (AF32) {
      const float* src = Af + (size_t)(bm + srow) * K + kt + sk;
      float fv[16];
#pragma unroll
      for (int i = 0; i < 4; i++)
        *(float4*)&fv[4 * i] = *(const float4*)(src + 4 * i);
      s16x8 h0, h1;
#pragma unroll
      for (int i = 0; i < 8; i++) { h0[i] = (short)f2bf(fv[i]); h1[i] = (short)f2bf(fv[8 + i]); }
      *(s16x8*)&As[srow * PK + sk] = h0;
      *(s16x8*)&As[srow * PK + sk + 8] = h1;
    } else {
      const unsigned short* src = Ab + (size_t)(bm + srow) * K + kt + sk;
      *(s16x8*)&As[srow * PK + sk]     = *(const s16x8*)src;
      *(s16x8*)&As[srow * PK + sk + 8] = *(const s16x8*)(src + 8);
    }
    {
      const unsigned short* src = BT + (size_t)(bn + srow) * K + kt + sk;
      *(s16x8*)&Bs[srow * PK + sk]     = *(const s16x8*)src;
      *(s16x8*)&Bs[srow * PK + sk + 8] = *(const s16x8*)(src + 8);
    }
    __syncthreads();
    s16x8 a0 = *(const s16x8*)&As[(wv * 32 + lc) * PK + lg * 8];
    s16x8 a1 = *(const s16x8*)&As[(wv * 32 + 16 + lc) * PK + lg * 8];
#pragma unroll
    for (int nt = 0; nt < 8; nt++) {
      s16x8 bfr = *(const s16x8*)&Bs[(nt * 16 + lc) * PK + lg * 8];
      acc[0][nt] = __builtin_amdgcn_mfma_f32_16x16x32_bf16(a0, bfr, acc[0][nt], 0, 0, 0);
      acc[1][nt] = __builtin_amdgcn_mfma_f32_16x16x32_bf16(a1, bfr, acc[1][nt], 0, 0, 0);
    }
  }

#pragma unroll
  for (int mt = 0; mt < 2; mt++) {
    const int rbase = bm + wv * 32 + mt * 16 + lg * 4;
#pragma unroll
    for (int nt = 0; nt < 8; nt++) {
      const int cg = bn + nt * 16 + lc;
#pragma unroll
      for (int r = 0; r < 4; r++) {
        const int rg = rbase + r;
        float val = acc[mt][nt][r] + bias[cg];
        if (EPI == 2) {
          ((float*)Cout)[(size_t)rg * N + cg] = val;
        } else {
          if (EPI == 1 && cg < 512) val *= 0.17677669529663687f;   // Q scale
          ((unsigned short*)Cout)[(size_t)rg * N + cg] = f2bf(val);
        }
      }
    }
  }
}

// ---------------- LayerNorm, IN PLACE on bf16 xa (wave per row) ----------------
__global__ __launch_bounds__(256) void ln_kernel(
    unsigned short* __restrict__ xa,
    const float* __restrict__ g_pt, const float* __restrict__ be_pt,
    const float* __restrict__ g_ps, const float* __restrict__ be_ps)
{
  const int row = blockIdx.x * 4 + (threadIdx.x >> 6);
  const int lane = threadIdx.x & 63;
  const bool isT = row < TROWS;
  const float* gg = isT ? g_pt : g_ps;
  const float* be = isT ? be_pt : be_ps;
  unsigned short* p = xa + (size_t)row * CDIM;
  float v[8];
  float s = 0.f, s2 = 0.f;
#pragma unroll
  for (int i = 0; i < 8; i++) {
    float xv = bf2f(p[i * 64 + lane]);
    v[i] = xv; s += xv; s2 += xv * xv;
  }
#pragma unroll
  for (int d = 1; d < 64; d <<= 1) { s += __shfl_xor(s, d); s2 += __shfl_xor(s2, d); }
  float mu = s * (1.f / CDIM);
  float var = s2 * (1.f / CDIM) - mu * mu;
  float rs = rsqrtf(var + 1e-5f);
#pragma unroll
  for (int i = 0; i < 8; i++) {
    int c = i * 64 + lane;
    p[c] = f2bf((v[i] - mu) * rs * gg[c] + be[c]);
  }
}

// ---------------- fused attention, one block per (window,head) in chunk ----------
// qkv: [CH_ROWS][1536] bf16 (q | k | v, each 16 heads x 32 dims).
__global__ __launch_bounds__(576) void attn_kernel(
    const unsigned short* __restrict__ qkv, const float* __restrict__ biasExp,
    const float* __restrict__ mask0, const float* __restrict__ mask1,
    unsigned short* __restrict__ outp, int c0w)
{
  __shared__ short VT[32 * 168];    // VT[d][k], k padded 144->160 (zeros)
  __shared__ short Ps[144 * 168];   // P[m][k], cols 144..159 zero
  const int wLocal = blockIdx.x >> 4, h = blockIdx.x & 15;
  const int b = c0w + wLocal;       // global window index
  const int t = threadIdx.x;
  const unsigned short* qb = qkv + (size_t)wLocal * NTOK * 1536;
  const int hq = h * 32;

  {  // stage V transposed (576 threads cover 144 rows x 4 chunks of 8)
    const int n = t >> 2, d0 = (t & 3) * 8;
    s16x8 vv = *(const s16x8*)&qb[(size_t)n * 1536 + 1024 + hq + d0];
#pragma unroll
    for (int i = 0; i < 8; i++) VT[(d0 + i) * 168 + n] = vv[i];
  }
  if (t < 512) VT[(t >> 4) * 168 + 144 + (t & 15)] = 0;          // all 32 pad rows
  for (int i = t; i < 144 * 16; i += 576) Ps[(i >> 4) * 168 + 144 + (i & 15)] = 0;
  __syncthreads();

  const int lane = t & 63, wv = t >> 6, lg = lane >> 4, lc = lane & 15;
  const f32x4 zero = {0.f, 0.f, 0.f, 0.f};

  // S = Q @ K^T  (wave's 16 rows x 144 cols, 9 MFMA)
  const s16x8 aq = *(const s16x8*)&qb[(size_t)(wv * 16 + lc) * 1536 + hq + lg * 8];
  f32x4 accS[9];
#pragma unroll
  for (int nt = 0; nt < 9; nt++) {
    s16x8 bk = *(const s16x8*)&qb[(size_t)(nt * 16 + lc) * 1536 + 512 + hq + lg * 8];
    accS[nt] = __builtin_amdgcn_mfma_f32_16x16x32_bf16(aq, bk, zero, 0, 0, 0);
  }

  const float* bptr = biasExp + (size_t)h * NTOK * NTOK;
  const float* mptr = (b < 64) ? (mask1 + (size_t)(b & 3) * NTOK * NTOK)
                               : (mask0 + (size_t)((b - 64) & 15) * NTOK * NTOK);
  const int mbase = wv * 16 + lg * 4;

#pragma unroll
  for (int r = 0; r < 4; r++) {
    const int m = mbase + r;
    const float* bm = bptr + m * NTOK;
    const float* mm = mptr + m * NTOK;
    float mx = -1e30f;
#pragma unroll
    for (int nt = 0; nt < 9; nt++) {
      float sv = accS[nt][r] + bm[nt * 16 + lc] + mm[nt * 16 + lc];
      accS[nt][r] = sv;
      mx = fmaxf(mx, sv);
    }
#pragma unroll
    for (int d = 1; d < 16; d <<= 1) mx = fmaxf(mx, __shfl_xor(mx, d));
    float sum = 0.f;
#pragma unroll
    for (int nt = 0; nt < 9; nt++) {
      float e = __expf(accS[nt][r] - mx);
      accS[nt][r] = e;
      sum += e;
    }
#pragma unroll
    for (int d = 1; d < 16; d <<= 1) sum += __shfl_xor(sum, d);
    float inv = 1.f / sum;
#pragma unroll
    for (int nt = 0; nt < 9; nt++)
      Ps[m * 168 + nt * 16 + lc] = (short)f2bf(accS[nt][r] * inv);
  }
  __syncthreads();

  // O = P @ V  (K padded to 160 with zeros)
#pragma unroll
  for (int dt = 0; dt < 2; dt++) {
    f32x4 accO = {0.f, 0.f, 0.f, 0.f};
#pragma unroll
    for (int kk = 0; kk < 5; kk++) {
      s16x8 ap = *(const s16x8*)&Ps[(wv * 16 + lc) * 168 + kk * 32 + lg * 8];
      s16x8 bv = *(const s16x8*)&VT[(dt * 16 + lc) * 168 + kk * 32 + lg * 8];
      accO = __builtin_amdgcn_mfma_f32_16x16x32_bf16(ap, bv, accO, 0, 0, 0);
    }
#pragma unroll
    for (int r = 0; r < 4; r++) {
      const int m = mbase + r;
      outp[(size_t)(b * NTOK + m) * CDIM + hq + dt * 16 + lc] = f2bf(accO[r]);
    }
  }
}

// ---------------- launch ----------------
extern "C" void kernel_launch(void* const* d_in, const int* in_sizes, int n_in,
                              void* d_out, int out_size, void* d_ws, size_t ws_size,
                              hipStream_t stream)
{
  const float* x     = (const float*)d_in[0];
  const float* tpl   = (const float*)d_in[1];
  const float* mask0 = (const float*)d_in[2];
  const float* mask1 = (const float*)d_in[3];
  const float* rpb   = (const float*)d_in[8];
  const float* w_ps  = (const float*)d_in[9];
  const float* b_ps  = (const float*)d_in[10];
  const float* g_ps  = (const float*)d_in[11];
  const float* be_ps = (const float*)d_in[12];
  const float* w_pt  = (const float*)d_in[13];
  const float* b_pt  = (const float*)d_in[14];
  const float* g_pt  = (const float*)d_in[15];
  const float* be_pt = (const float*)d_in[16];
  const float* w_qkv = (const float*)d_in[17];
  const float* b_qkv = (const float*)d_in[18];
  const float* w_tr  = (const float*)d_in[19];
  const float* b_tr  = (const float*)d_in[20];
  const float* w_sr  = (const float*)d_in[21];
  const float* b_sr  = (const float*)d_in[22];

  // ws layout — TOTAL ~91MB:
  char* ws = (char*)d_ws;
  unsigned short* wpsT  = (unsigned short*)(ws + 0x0000000);  // 1MB
  unsigned short* wptT  = (unsigned short*)(ws + 0x0100000);  // 1MB
  unsigned short* wqkvT = (unsigned short*)(ws + 0x0200000);  // 1.5MB
  unsigned short* wtrT  = (unsigned short*)(ws + 0x0380000);  // 1MB
  unsigned short* wsrT  = (unsigned short*)(ws + 0x0480000);  // 1MB
  float* biasExp        = (float*)(ws + 0x0580000);           // 1.33MB
  unsigned short* xa    = (unsigned short*)(ws + 0x0700000);  // 45MB [46080][512] (also attnO)
  unsigned short* qkvC  = (unsigned short*)(ws + 0x3500000);  // 33.75MB [11520][1536]
  float* outb           = (float*)d_out;                      // FLOAT32 output

  transpose_cast<<<2048, 256, 0, stream>>>(w_ps, wpsT, 1024, 512);
  transpose_cast<<<2048, 256, 0, stream>>>(w_pt, wptT, 1024, 512);
  transpose_cast<<<3072, 256, 0, stream>>>(w_qkv, wqkvT, 512, 1536);
  transpose_cast<<<2048, 256, 0, stream>>>(w_tr, wtrT, 512, 1024);
  transpose_cast<<<2048, 256, 0, stream>>>(w_sr, wsrT, 512, 1024);
  expand_bias<<<(NHEADS * NTOK * NTOK + 255) / 256, 256, 0, stream>>>(rpb, biasExp);

  // projection GEMMs (A f32) -> xa bf16 (bias added here; LN scale/shift later)
  gemm128<1, 0><<<dim3(72, 4), 256, 0, stream>>>(tpl, wptT, b_pt, xa, TROWS, CDIM, 1024);
  gemm128<1, 0><<<dim3(288, 4), 256, 0, stream>>>(x, wpsT, b_ps, xa + (size_t)TROWS * CDIM,
                                                  SROWS, CDIM, 1024);
  // LayerNorm in place on xa
  ln_kernel<<<TOTROWS / 4, 256, 0, stream>>>(xa, g_pt, be_pt, g_ps, be_ps);

  // chunked QKV + attention (attn writes back into consumed xa rows)
  for (int c = 0; c < NCHUNK; c++) {
    gemm128<0, 1><<<dim3(CH_ROWS / 128, 12), 256, 0, stream>>>(
        xa + (size_t)c * CH_ROWS * CDIM, wqkvT, b_qkv, qkvC, CH_ROWS, 1536, CDIM);
    attn_kernel<<<CH_WIN * NHEADS, 576, 0, stream>>>(
        qkvC, biasExp, mask0, mask1, xa, c * CH_WIN);
  }

  // output GEMMs -> d_out (FLOAT32): template rows then search rows
  gemm128<0, 2><<<dim3(72, 8), 256, 0, stream>>>(xa, wtrT, b_tr, outb, TROWS, 1024, CDIM);
  gemm128<0, 2><<<dim3(288, 8), 256, 0, stream>>>(xa + (size_t)TROWS * CDIM, wsrT, b_sr,
                                                  outb + (size_t)TROWS * 1024, SROWS, 1024, CDIM);
}

// Round 7
// 610.598 us; speedup vs baseline: 1.0206x; 1.0206x over previous
//
#include <hip/hip_runtime.h>

// MixingAttention on MI355X (gfx950) — ROUND 7.
// r6 passed (623us). This round: all GEMMs -> m97 structure (global_load_lds
// width=16, linear LDS, 128x128xBK32), f32 inputs pre-cast to bf16 (chunked),
// LayerNorm vectorized (short8).

using s16x8 = __attribute__((ext_vector_type(8))) short;   // 8 bf16
using f32x4 = __attribute__((ext_vector_type(4))) float;   // 4 f32 acc

#define NTOK 144
#define NHEADS 16
#define CDIM 512
#define TROWS 9216     // 64*144 template rows
#define SROWS 36864    // 256*144 search rows
#define TOTROWS 46080
#define CH_WIN 80
#define CH_ROWS (CH_WIN * NTOK)   // 11520
#define NCHUNK 4

__device__ __forceinline__ unsigned short f2bf(float f) {
  unsigned u = __float_as_uint(f);
  u += 0x7fffu + ((u >> 16) & 1u);     // RNE
  return (unsigned short)(u >> 16);
}
__device__ __forceinline__ float bf2f(unsigned short u) {
  return __uint_as_float(((unsigned)u) << 16);
}

// async global->LDS, 16B per lane; lds base must be wave-uniform.
__device__ __forceinline__ void gld16(const unsigned short* g, short* l) {
  __builtin_amdgcn_global_load_lds(
      (const __attribute__((address_space(1))) unsigned int*)g,
      (__attribute__((address_space(3))) unsigned int*)l, 16, 0, 0);
}

// ---------------- prep kernels ----------------

// w: (Kd, Nd) f32 row-major  ->  wT: (Nd, Kd) bf16 row-major
__global__ void transpose_cast(const float* __restrict__ w,
                               unsigned short* __restrict__ wT, int Kd, int Nd) {
  int i = blockIdx.x * 256 + threadIdx.x;
  if (i >= Kd * Nd) return;
  int n = i / Kd, k = i % Kd;
  wT[i] = f2bf(w[(size_t)k * Nd + n]);
}

// f32 -> bf16 bulk cast, 8 elems/thread (32B in, 16B out)
__global__ __launch_bounds__(256) void cast_bf16(const float* __restrict__ in,
                                                 unsigned short* __restrict__ out, int n8) {
  int i = blockIdx.x * 256 + threadIdx.x;
  if (i >= n8) return;
  const float4* p = (const float4*)in + (size_t)i * 2;
  float4 f0 = p[0], f1 = p[1];
  s16x8 o;
  o[0] = (short)f2bf(f0.x); o[1] = (short)f2bf(f0.y);
  o[2] = (short)f2bf(f0.z); o[3] = (short)f2bf(f0.w);
  o[4] = (short)f2bf(f1.x); o[5] = (short)f2bf(f1.y);
  o[6] = (short)f2bf(f1.z); o[7] = (short)f2bf(f1.w);
  *(s16x8*)&out[(size_t)i * 8] = o;
}

// biasExp[h][i][j] = rpb[((ih-jh+11)*23 + (iw-jw+11))*16 + h]
__global__ void expand_bias(const float* __restrict__ rpb, float* __restrict__ biasExp) {
  int i = blockIdx.x * 256 + threadIdx.x;
  if (i >= NHEADS * NTOK * NTOK) return;
  int h = i / (NTOK * NTOK);
  int rem = i % (NTOK * NTOK);
  int qi = rem / NTOK, kj = rem % NTOK;
  int dh = qi / 12 - kj / 12 + 11;
  int dw = qi % 12 - kj % 12 + 11;
  biasExp[i] = rpb[(dh * 23 + dw) * NHEADS + h];
}

// ---------------- m97-structure MFMA GEMM (global_load_lds staging) ----------
// C(M,N) = A(M,K) @ B(K,N); A bf16 (M,K), B pre-transposed BT(N,K) bf16.
// EPI 0: +bias[col], store bf16.
// EPI 1: +bias[col], scale cols<512 by 32^-0.5 (Q), store bf16 (qkv).
// EPI 2: +bias[col], store f32 (final outputs -> d_out).
template<int EPI>
__global__ __launch_bounds__(256) void gemm_glds(
    const unsigned short* __restrict__ Ab, const unsigned short* __restrict__ BT,
    const float* __restrict__ bias, void* __restrict__ Cout,
    int M, int N, int K)
{
  __shared__ short As[128 * 32];   // linear [row][32], no pad (gload_lds needs it)
  __shared__ short Bs[128 * 32];
  const int t = threadIdx.x;
  const int lane = t & 63, wv = t >> 6, lg = lane >> 4, lc = lane & 15;
  const int bm = blockIdx.x * 128, bn = blockIdx.y * 128;

  // staging: instr j covers rows [j*64 + wv*16, +16), lane l -> row j*64+wv*16+(l>>2),
  // col (l&3)*8; LDS dest base (uniform per wave): shorts j*2048 + wv*512.
  const int srow = wv * 16 + (lane >> 2);
  const int scol = (lane & 3) * 8;
  const unsigned short* aSrc = Ab + (size_t)(bm + srow) * K + scol;
  const unsigned short* bSrc = BT + (size_t)(bn + srow) * K + scol;
  const size_t rowK64 = (size_t)64 * K;

  f32x4 acc[2][8] = {};

  for (int kt = 0; kt < K; kt += 32) {
    __syncthreads();                       // prev tile's reads done
    gld16(aSrc + kt,          &As[wv * 512]);
    gld16(aSrc + kt + rowK64, &As[2048 + wv * 512]);
    gld16(bSrc + kt,          &Bs[wv * 512]);
    gld16(bSrc + kt + rowK64, &Bs[2048 + wv * 512]);
    __syncthreads();                       // compiler drains vmcnt before barrier
    s16x8 a0 = *(const s16x8*)&As[(wv * 32 + lc) * 32 + lg * 8];
    s16x8 a1 = *(const s16x8*)&As[(wv * 32 + 16 + lc) * 32 + lg * 8];
#pragma unroll
    for (int nt = 0; nt < 8; nt++) {
      s16x8 bfr = *(const s16x8*)&Bs[(nt * 16 + lc) * 32 + lg * 8];
      acc[0][nt] = __builtin_amdgcn_mfma_f32_16x16x32_bf16(a0, bfr, acc[0][nt], 0, 0, 0);
      acc[1][nt] = __builtin_amdgcn_mfma_f32_16x16x32_bf16(a1, bfr, acc[1][nt], 0, 0, 0);
    }
  }

#pragma unroll
  for (int mt = 0; mt < 2; mt++) {
    const int rbase = bm + wv * 32 + mt * 16 + lg * 4;
#pragma unroll
    for (int nt = 0; nt < 8; nt++) {
      const int cg = bn + nt * 16 + lc;
#pragma unroll
      for (int r = 0; r < 4; r++) {
        const int rg = rbase + r;
        float val = acc[mt][nt][r] + bias[cg];
        if (EPI == 2) {
          ((float*)Cout)[(size_t)rg * N + cg] = val;
        } else {
          if (EPI == 1 && cg < 512) val *= 0.17677669529663687f;   // Q scale
          ((unsigned short*)Cout)[(size_t)rg * N + cg] = f2bf(val);
        }
      }
    }
  }
}

// ---------------- LayerNorm, in place, vectorized (wave per row) ----------------
__global__ __launch_bounds__(256) void ln_kernel(
    unsigned short* __restrict__ xa,
    const float* __restrict__ g_pt, const float* __restrict__ be_pt,
    const float* __restrict__ g_ps, const float* __restrict__ be_ps)
{
  const int row = blockIdx.x * 4 + (threadIdx.x >> 6);
  const int lane = threadIdx.x & 63;
  const bool isT = row < TROWS;
  const float* gg = isT ? g_pt : g_ps;
  const float* be = isT ? be_pt : be_ps;
  unsigned short* p = xa + (size_t)row * CDIM;
  const int c0 = lane * 8;

  s16x8 v8 = *(const s16x8*)&p[c0];
  float f[8];
  float s = 0.f, s2 = 0.f;
#pragma unroll
  for (int i = 0; i < 8; i++) {
    float xv = bf2f((unsigned short)v8[i]);
    f[i] = xv; s += xv; s2 += xv * xv;
  }
#pragma unroll
  for (int d = 1; d < 64; d <<= 1) { s += __shfl_xor(s, d); s2 += __shfl_xor(s2, d); }
  float mu = s * (1.f / CDIM);
  float var = s2 * (1.f / CDIM) - mu * mu;
  float rs = rsqrtf(var + 1e-5f);

  float4 g0 = *(const float4*)&gg[c0], g1 = *(const float4*)&gg[c0 + 4];
  float4 e0 = *(const float4*)&be[c0], e1 = *(const float4*)&be[c0 + 4];
  float gv[8] = {g0.x, g0.y, g0.z, g0.w, g1.x, g1.y, g1.z, g1.w};
  float ev[8] = {e0.x, e0.y, e0.z, e0.w, e1.x, e1.y, e1.z, e1.w};
  s16x8 o;
#pragma unroll
  for (int i = 0; i < 8; i++)
    o[i] = (short)f2bf((f[i] - mu) * rs * gv[i] + ev[i]);
  *(s16x8*)&p[c0] = o;
}

// ---------------- fused attention, one block per (window,head) in chunk ----------
// qkv: [CH_ROWS][1536] bf16 (q | k | v, each 16 heads x 32 dims).
__global__ __launch_bounds__(576) void attn_kernel(
    const unsigned short* __restrict__ qkv, const float* __restrict__ biasExp,
    const float* __restrict__ mask0, const float* __restrict__ mask1,
    unsigned short* __restrict__ outp, int c0w)
{
  __shared__ short VT[32 * 168];    // VT[d][k], k padded 144->160 (zeros)
  __shared__ short Ps[144 * 168];   // P[m][k], cols 144..159 zero
  const int wLocal = blockIdx.x >> 4, h = blockIdx.x & 15;
  const int b = c0w + wLocal;       // global window index
  const int t = threadIdx.x;
  const unsigned short* qb = qkv + (size_t)wLocal * NTOK * 1536;
  const int hq = h * 32;

  {  // stage V transposed
    const int n = t >> 2, d0 = (t & 3) * 8;
    s16x8 vv = *(const s16x8*)&qb[(size_t)n * 1536 + 1024 + hq + d0];
#pragma unroll
    for (int i = 0; i < 8; i++) VT[(d0 + i) * 168 + n] = vv[i];
  }
  if (t < 512) VT[(t >> 4) * 168 + 144 + (t & 15)] = 0;          // all 32 pad rows
  for (int i = t; i < 144 * 16; i += 576) Ps[(i >> 4) * 168 + 144 + (i & 15)] = 0;
  __syncthreads();

  const int lane = t & 63, wv = t >> 6, lg = lane >> 4, lc = lane & 15;
  const f32x4 zero = {0.f, 0.f, 0.f, 0.f};

  // S = Q @ K^T  (wave's 16 rows x 144 cols, 9 MFMA)
  const s16x8 aq = *(const s16x8*)&qb[(size_t)(wv * 16 + lc) * 1536 + hq + lg * 8];
  f32x4 accS[9];
#pragma unroll
  for (int nt = 0; nt < 9; nt++) {
    s16x8 bk = *(const s16x8*)&qb[(size_t)(nt * 16 + lc) * 1536 + 512 + hq + lg * 8];
    accS[nt] = __builtin_amdgcn_mfma_f32_16x16x32_bf16(aq, bk, zero, 0, 0, 0);
  }

  const float* bptr = biasExp + (size_t)h * NTOK * NTOK;
  const float* mptr = (b < 64) ? (mask1 + (size_t)(b & 3) * NTOK * NTOK)
                               : (mask0 + (size_t)((b - 64) & 15) * NTOK * NTOK);
  const int mbase = wv * 16 + lg * 4;

#pragma unroll
  for (int r = 0; r < 4; r++) {
    const int m = mbase + r;
    const float* bm = bptr + m * NTOK;
    const float* mm = mptr + m * NTOK;
    float mx = -1e30f;
#pragma unroll
    for (int nt = 0; nt < 9; nt++) {
      float sv = accS[nt][r] + bm[nt * 16 + lc] + mm[nt * 16 + lc];
      accS[nt][r] = sv;
      mx = fmaxf(mx, sv);
    }
#pragma unroll
    for (int d = 1; d < 16; d <<= 1) mx = fmaxf(mx, __shfl_xor(mx, d));
    float sum = 0.f;
#pragma unroll
    for (int nt = 0; nt < 9; nt++) {
      float e = __expf(accS[nt][r] - mx);
      accS[nt][r] = e;
      sum += e;
    }
#pragma unroll
    for (int d = 1; d < 16; d <<= 1) sum += __shfl_xor(sum, d);
    float inv = 1.f / sum;
#pragma unroll
    for (int nt = 0; nt < 9; nt++)
      Ps[m * 168 + nt * 16 + lc] = (short)f2bf(accS[nt][r] * inv);
  }
  __syncthreads();

  // O = P @ V  (K padded to 160 with zeros)
#pragma unroll
  for (int dt = 0; dt < 2; dt++) {
    f32x4 accO = {0.f, 0.f, 0.f, 0.f};
#pragma unroll
    for (int kk = 0; kk < 5; kk++) {
      s16x8 ap = *(const s16x8*)&Ps[(wv * 16 + lc) * 168 + kk * 32 + lg * 8];
      s16x8 bv = *(const s16x8*)&VT[(dt * 16 + lc) * 168 + kk * 32 + lg * 8];
      accO = __builtin_amdgcn_mfma_f32_16x16x32_bf16(ap, bv, accO, 0, 0, 0);
    }
#pragma unroll
    for (int r = 0; r < 4; r++) {
      const int m = mbase + r;
      outp[(size_t)(b * NTOK + m) * CDIM + hq + dt * 16 + lc] = f2bf(accO[r]);
    }
  }
}

// ---------------- launch ----------------
extern "C" void kernel_launch(void* const* d_in, const int* in_sizes, int n_in,
                              void* d_out, int out_size, void* d_ws, size_t ws_size,
                              hipStream_t stream)
{
  const float* x     = (const float*)d_in[0];
  const float* tpl   = (const float*)d_in[1];
  const float* mask0 = (const float*)d_in[2];
  const float* mask1 = (const float*)d_in[3];
  const float* rpb   = (const float*)d_in[8];
  const float* w_ps  = (const float*)d_in[9];
  const float* b_ps  = (const float*)d_in[10];
  const float* g_ps  = (const float*)d_in[11];
  const float* be_ps = (const float*)d_in[12];
  const float* w_pt  = (const float*)d_in[13];
  const float* b_pt  = (const float*)d_in[14];
  const float* g_pt  = (const float*)d_in[15];
  const float* be_pt = (const float*)d_in[16];
  const float* w_qkv = (const float*)d_in[17];
  const float* b_qkv = (const float*)d_in[18];
  const float* w_tr  = (const float*)d_in[19];
  const float* b_tr  = (const float*)d_in[20];
  const float* w_sr  = (const float*)d_in[21];
  const float* b_sr  = (const float*)d_in[22];

  // ws layout — peak ~88MB:
  char* ws = (char*)d_ws;
  unsigned short* wpsT  = (unsigned short*)(ws + 0x0000000);  // 1MB
  unsigned short* wptT  = (unsigned short*)(ws + 0x0100000);  // 1MB
  unsigned short* wqkvT = (unsigned short*)(ws + 0x0200000);  // 1.5MB
  unsigned short* wtrT  = (unsigned short*)(ws + 0x0380000);  // 1MB
  unsigned short* wsrT  = (unsigned short*)(ws + 0x0480000);  // 1MB
  float* biasExp        = (float*)(ws + 0x0580000);           // 1.33MB
  unsigned short* xa    = (unsigned short*)(ws + 0x0700000);  // 45MB [46080][512]
  unsigned short* S     = (unsigned short*)(ws + 0x3400000);  // 36MB scratch (cast chunks / qkvC)
  float* outb           = (float*)d_out;                      // FLOAT32 output

  transpose_cast<<<2048, 256, 0, stream>>>(w_ps, wpsT, 1024, 512);
  transpose_cast<<<2048, 256, 0, stream>>>(w_pt, wptT, 1024, 512);
  transpose_cast<<<3072, 256, 0, stream>>>(w_qkv, wqkvT, 512, 1536);
  transpose_cast<<<2048, 256, 0, stream>>>(w_tr, wtrT, 512, 1024);
  transpose_cast<<<2048, 256, 0, stream>>>(w_sr, wsrT, 512, 1024);
  expand_bias<<<(NHEADS * NTOK * NTOK + 255) / 256, 256, 0, stream>>>(rpb, biasExp);

  // projection GEMMs, chunked: cast f32->bf16 into S, then m97-GEMM
  {
    // template: 9216 rows
    cast_bf16<<<(TROWS * 1024 / 8 + 255) / 256, 256, 0, stream>>>(tpl, S, TROWS * 1024 / 8);
    gemm_glds<0><<<dim3(72, 4), 256, 0, stream>>>(S, wptT, b_pt, xa, TROWS, CDIM, 1024);
    // search: 2 x 18432 rows
    for (int c = 0; c < 2; c++) {
      const int rows = 18432;
      cast_bf16<<<(rows * 1024 / 8 + 255) / 256, 256, 0, stream>>>(
          x + (size_t)c * rows * 1024, S, rows * 1024 / 8);
      gemm_glds<0><<<dim3(rows / 128, 4), 256, 0, stream>>>(
          S, wpsT, b_ps, xa + (size_t)(TROWS + c * rows) * CDIM, rows, CDIM, 1024);
    }
  }

  // LayerNorm in place on xa
  ln_kernel<<<TOTROWS / 4, 256, 0, stream>>>(xa, g_pt, be_pt, g_ps, be_ps);

  // chunked QKV + attention (attn writes back into consumed xa rows)
  for (int c = 0; c < NCHUNK; c++) {
    gemm_glds<1><<<dim3(CH_ROWS / 128, 12), 256, 0, stream>>>(
        xa + (size_t)c * CH_ROWS * CDIM, wqkvT, b_qkv, S, CH_ROWS, 1536, CDIM);
    attn_kernel<<<CH_WIN * NHEADS, 576, 0, stream>>>(
        S, biasExp, mask0, mask1, xa, c * CH_WIN);
  }

  // output GEMMs -> d_out (f32): template rows then search rows
  gemm_glds<2><<<dim3(72, 8), 256, 0, stream>>>(xa, wtrT, b_tr, outb, TROWS, 1024, CDIM);
  gemm_glds<2><<<dim3(288, 8), 256, 0, stream>>>(xa + (size_t)TROWS * CDIM, wsrT, b_sr,
                                                 outb + (size_t)TROWS * 1024, SROWS, 1024, CDIM);
}

// Round 8
// 567.388 us; speedup vs baseline: 1.0983x; 1.0762x over previous
//
#include <hip/hip_runtime.h>

// MixingAttention on MI355X (gfx950) — ROUND 8.
// ws_size = 720MiB (fill evidence) -> un-chunk everything; merge GEMM pairs
// (per-row-block weight select); combined bias+mask bf16 table for attention.

using s16x8 = __attribute__((ext_vector_type(8))) short;   // 8 bf16
using f32x4 = __attribute__((ext_vector_type(4))) float;   // 4 f32 acc

#define NTOK 144
#define NHEADS 16
#define CDIM 512
#define TROWS 9216     // 64*144 template rows
#define SROWS 36864    // 256*144 search rows
#define TOTROWS 46080
#define NWIN 320
#define NCLS 20        // 4 (mask1) + 16 (mask0) mask classes

__device__ __forceinline__ unsigned short f2bf(float f) {
  unsigned u = __float_as_uint(f);
  u += 0x7fffu + ((u >> 16) & 1u);     // RNE
  return (unsigned short)(u >> 16);
}
__device__ __forceinline__ float bf2f(unsigned short u) {
  return __uint_as_float(((unsigned)u) << 16);
}

// async global->LDS, 16B per lane; lds base must be wave-uniform.
__device__ __forceinline__ void gld16(const unsigned short* g, short* l) {
  __builtin_amdgcn_global_load_lds(
      (const __attribute__((address_space(1))) unsigned int*)g,
      (__attribute__((address_space(3))) unsigned int*)l, 16, 0, 0);
}

// ---------------- prep kernels ----------------

// w: (Kd, Nd) f32 row-major  ->  wT: (Nd, Kd) bf16 row-major
__global__ void transpose_cast(const float* __restrict__ w,
                               unsigned short* __restrict__ wT, int Kd, int Nd) {
  int i = blockIdx.x * 256 + threadIdx.x;
  if (i >= Kd * Nd) return;
  int n = i / Kd, k = i % Kd;
  wT[i] = f2bf(w[(size_t)k * Nd + n]);
}

// f32 -> bf16 bulk cast, 8 elems/thread
__global__ __launch_bounds__(256) void cast_bf16(const float* __restrict__ in,
                                                 unsigned short* __restrict__ out, int n8) {
  int i = blockIdx.x * 256 + threadIdx.x;
  if (i >= n8) return;
  const float4* p = (const float4*)in + (size_t)i * 2;
  float4 f0 = p[0], f1 = p[1];
  s16x8 o;
  o[0] = (short)f2bf(f0.x); o[1] = (short)f2bf(f0.y);
  o[2] = (short)f2bf(f0.z); o[3] = (short)f2bf(f0.w);
  o[4] = (short)f2bf(f1.x); o[5] = (short)f2bf(f1.y);
  o[6] = (short)f2bf(f1.z); o[7] = (short)f2bf(f1.w);
  *(s16x8*)&out[(size_t)i * 8] = o;
}

// cmb[cls][h][qi][kj] = rel-pos-bias(h,qi,kj) + mask(cls,qi,kj), bf16
__global__ void build_cmb(const float* __restrict__ rpb, const float* __restrict__ m0,
                          const float* __restrict__ m1, unsigned short* __restrict__ cmb) {
  int i = blockIdx.x * 256 + threadIdx.x;
  if (i >= NCLS * NHEADS * NTOK * NTOK) return;
  int cls = i / (NHEADS * NTOK * NTOK);
  int rem = i % (NHEADS * NTOK * NTOK);
  int h = rem / (NTOK * NTOK);
  int ij = rem % (NTOK * NTOK);
  int qi = ij / NTOK, kj = ij % NTOK;
  int dh = qi / 12 - kj / 12 + 11;
  int dw = qi % 12 - kj % 12 + 11;
  float bias = rpb[(dh * 23 + dw) * NHEADS + h];
  float mv = (cls < 4) ? m1[(size_t)cls * NTOK * NTOK + ij]
                       : m0[(size_t)(cls - 4) * NTOK * NTOK + ij];
  cmb[i] = f2bf(bias + mv);
}

// ---------------- m97-structure MFMA GEMM (global_load_lds staging) ----------
// C(M,N) = A(M,K) @ B(K,N); per-row-block select: rows < TROWS use BTt/biast.
// EPI 0: +bias, store bf16.  EPI 1: +bias, Q-scale cols<512, store bf16.
// EPI 2: +bias, store f32.
template<int EPI>
__global__ __launch_bounds__(256) void gemm_glds(
    const unsigned short* __restrict__ Ab,
    const unsigned short* __restrict__ BTt, const unsigned short* __restrict__ BTs,
    const float* __restrict__ biast, const float* __restrict__ biass,
    void* __restrict__ Cout, int M, int N, int K)
{
  __shared__ short As[128 * 32];   // linear [row][32], no pad (gload_lds needs it)
  __shared__ short Bs[128 * 32];
  const int t = threadIdx.x;
  const int lane = t & 63, wv = t >> 6, lg = lane >> 4, lc = lane & 15;
  const int bm = blockIdx.x * 128, bn = blockIdx.y * 128;
  const bool isT = bm < TROWS;
  const unsigned short* BT = isT ? BTt : BTs;
  const float* bias = isT ? biast : biass;

  const int srow = wv * 16 + (lane >> 2);
  const int scol = (lane & 3) * 8;
  const unsigned short* aSrc = Ab + (size_t)(bm + srow) * K + scol;
  const unsigned short* bSrc = BT + (size_t)(bn + srow) * K + scol;
  const size_t rowK64 = (size_t)64 * K;

  f32x4 acc[2][8] = {};

  for (int kt = 0; kt < K; kt += 32) {
    __syncthreads();
    gld16(aSrc + kt,          &As[wv * 512]);
    gld16(aSrc + kt + rowK64, &As[2048 + wv * 512]);
    gld16(bSrc + kt,          &Bs[wv * 512]);
    gld16(bSrc + kt + rowK64, &Bs[2048 + wv * 512]);
    __syncthreads();
    s16x8 a0 = *(const s16x8*)&As[(wv * 32 + lc) * 32 + lg * 8];
    s16x8 a1 = *(const s16x8*)&As[(wv * 32 + 16 + lc) * 32 + lg * 8];
#pragma unroll
    for (int nt = 0; nt < 8; nt++) {
      s16x8 bfr = *(const s16x8*)&Bs[(nt * 16 + lc) * 32 + lg * 8];
      acc[0][nt] = __builtin_amdgcn_mfma_f32_16x16x32_bf16(a0, bfr, acc[0][nt], 0, 0, 0);
      acc[1][nt] = __builtin_amdgcn_mfma_f32_16x16x32_bf16(a1, bfr, acc[1][nt], 0, 0, 0);
    }
  }

#pragma unroll
  for (int mt = 0; mt < 2; mt++) {
    const int rbase = bm + wv * 32 + mt * 16 + lg * 4;
#pragma unroll
    for (int nt = 0; nt < 8; nt++) {
      const int cg = bn + nt * 16 + lc;
#pragma unroll
      for (int r = 0; r < 4; r++) {
        const int rg = rbase + r;
        float val = acc[mt][nt][r] + bias[cg];
        if (EPI == 2) {
          ((float*)Cout)[(size_t)rg * N + cg] = val;
        } else {
          if (EPI == 1 && cg < 512) val *= 0.17677669529663687f;   // Q scale
          ((unsigned short*)Cout)[(size_t)rg * N + cg] = f2bf(val);
        }
      }
    }
  }
}

// ---------------- LayerNorm, in place, vectorized (wave per row) ----------------
__global__ __launch_bounds__(256) void ln_kernel(
    unsigned short* __restrict__ xa,
    const float* __restrict__ g_pt, const float* __restrict__ be_pt,
    const float* __restrict__ g_ps, const float* __restrict__ be_ps)
{
  const int row = blockIdx.x * 4 + (threadIdx.x >> 6);
  const int lane = threadIdx.x & 63;
  const bool isT = row < TROWS;
  const float* gg = isT ? g_pt : g_ps;
  const float* be = isT ? be_pt : be_ps;
  unsigned short* p = xa + (size_t)row * CDIM;
  const int c0 = lane * 8;

  s16x8 v8 = *(const s16x8*)&p[c0];
  float f[8];
  float s = 0.f, s2 = 0.f;
#pragma unroll
  for (int i = 0; i < 8; i++) {
    float xv = bf2f((unsigned short)v8[i]);
    f[i] = xv; s += xv; s2 += xv * xv;
  }
#pragma unroll
  for (int d = 1; d < 64; d <<= 1) { s += __shfl_xor(s, d); s2 += __shfl_xor(s2, d); }
  float mu = s * (1.f / CDIM);
  float var = s2 * (1.f / CDIM) - mu * mu;
  float rs = rsqrtf(var + 1e-5f);

  float4 g0 = *(const float4*)&gg[c0], g1 = *(const float4*)&gg[c0 + 4];
  float4 e0 = *(const float4*)&be[c0], e1 = *(const float4*)&be[c0 + 4];
  float gv[8] = {g0.x, g0.y, g0.z, g0.w, g1.x, g1.y, g1.z, g1.w};
  float ev[8] = {e0.x, e0.y, e0.z, e0.w, e1.x, e1.y, e1.z, e1.w};
  s16x8 o;
#pragma unroll
  for (int i = 0; i < 8; i++)
    o[i] = (short)f2bf((f[i] - mu) * rs * gv[i] + ev[i]);
  *(s16x8*)&p[c0] = o;
}

// ---------------- fused attention, one block per (window, head) ----------------
// qkv: [TOTROWS][1536] bf16 (q | k | v, each 16 heads x 32 dims).
__global__ __launch_bounds__(576) void attn_kernel(
    const unsigned short* __restrict__ qkv, const unsigned short* __restrict__ cmb,
    unsigned short* __restrict__ outp)
{
  __shared__ short VT[32 * 168];    // VT[d][k], k padded 144->160 (zeros)
  __shared__ short Ps[144 * 168];   // P[m][k], cols 144..159 zero
  const int w = blockIdx.x >> 4, h = blockIdx.x & 15;
  const int t = threadIdx.x;
  const unsigned short* qb = qkv + (size_t)w * NTOK * 1536;
  const int hq = h * 32;

  {  // stage V transposed
    const int n = t >> 2, d0 = (t & 3) * 8;
    s16x8 vv = *(const s16x8*)&qb[(size_t)n * 1536 + 1024 + hq + d0];
#pragma unroll
    for (int i = 0; i < 8; i++) VT[(d0 + i) * 168 + n] = vv[i];
  }
  if (t < 512) VT[(t >> 4) * 168 + 144 + (t & 15)] = 0;
  for (int i = t; i < 144 * 16; i += 576) Ps[(i >> 4) * 168 + 144 + (i & 15)] = 0;
  __syncthreads();

  const int lane = t & 63, wv = t >> 6, lg = lane >> 4, lc = lane & 15;
  const f32x4 zero = {0.f, 0.f, 0.f, 0.f};

  // S = Q @ K^T  (wave's 16 rows x 144 cols, 9 MFMA)
  const s16x8 aq = *(const s16x8*)&qb[(size_t)(wv * 16 + lc) * 1536 + hq + lg * 8];
  f32x4 accS[9];
#pragma unroll
  for (int nt = 0; nt < 9; nt++) {
    s16x8 bk = *(const s16x8*)&qb[(size_t)(nt * 16 + lc) * 1536 + 512 + hq + lg * 8];
    accS[nt] = __builtin_amdgcn_mfma_f32_16x16x32_bf16(aq, bk, zero, 0, 0, 0);
  }

  const int cls = (w < 64) ? (w & 3) : 4 + ((w - 64) & 15);
  const unsigned short* cptr = cmb + ((size_t)cls * NHEADS + h) * (NTOK * NTOK);
  const int mbase = wv * 16 + lg * 4;

#pragma unroll
  for (int r = 0; r < 4; r++) {
    const int m = mbase + r;
    const unsigned short* cm = cptr + m * NTOK;
    float mx = -1e30f;
#pragma unroll
    for (int nt = 0; nt < 9; nt++) {
      float sv = accS[nt][r] + bf2f(cm[nt * 16 + lc]);
      accS[nt][r] = sv;
      mx = fmaxf(mx, sv);
    }
#pragma unroll
    for (int d = 1; d < 16; d <<= 1) mx = fmaxf(mx, __shfl_xor(mx, d));
    float sum = 0.f;
#pragma unroll
    for (int nt = 0; nt < 9; nt++) {
      float e = __expf(accS[nt][r] - mx);
      accS[nt][r] = e;
      sum += e;
    }
#pragma unroll
    for (int d = 1; d < 16; d <<= 1) sum += __shfl_xor(sum, d);
    float inv = 1.f / sum;
#pragma unroll
    for (int nt = 0; nt < 9; nt++)
      Ps[m * 168 + nt * 16 + lc] = (short)f2bf(accS[nt][r] * inv);
  }
  __syncthreads();

  // O = P @ V  (K padded to 160 with zeros)
#pragma unroll
  for (int dt = 0; dt < 2; dt++) {
    f32x4 accO = {0.f, 0.f, 0.f, 0.f};
#pragma unroll
    for (int kk = 0; kk < 5; kk++) {
      s16x8 ap = *(const s16x8*)&Ps[(wv * 16 + lc) * 168 + kk * 32 + lg * 8];
      s16x8 bv = *(const s16x8*)&VT[(dt * 16 + lc) * 168 + kk * 32 + lg * 8];
      accO = __builtin_amdgcn_mfma_f32_16x16x32_bf16(ap, bv, accO, 0, 0, 0);
    }
#pragma unroll
    for (int r = 0; r < 4; r++) {
      const int m = mbase + r;
      outp[(size_t)(w * NTOK + m) * CDIM + hq + dt * 16 + lc] = f2bf(accO[r]);
    }
  }
}

// ---------------- launch ----------------
extern "C" void kernel_launch(void* const* d_in, const int* in_sizes, int n_in,
                              void* d_out, int out_size, void* d_ws, size_t ws_size,
                              hipStream_t stream)
{
  const float* x     = (const float*)d_in[0];
  const float* tpl   = (const float*)d_in[1];
  const float* mask0 = (const float*)d_in[2];
  const float* mask1 = (const float*)d_in[3];
  const float* rpb   = (const float*)d_in[8];
  const float* w_ps  = (const float*)d_in[9];
  const float* b_ps  = (const float*)d_in[10];
  const float* g_ps  = (const float*)d_in[11];
  const float* be_ps = (const float*)d_in[12];
  const float* w_pt  = (const float*)d_in[13];
  const float* b_pt  = (const float*)d_in[14];
  const float* g_pt  = (const float*)d_in[15];
  const float* be_pt = (const float*)d_in[16];
  const float* w_qkv = (const float*)d_in[17];
  const float* b_qkv = (const float*)d_in[18];
  const float* w_tr  = (const float*)d_in[19];
  const float* b_tr  = (const float*)d_in[20];
  const float* w_sr  = (const float*)d_in[21];
  const float* b_sr  = (const float*)d_in[22];

  // ws layout (~208MB of 720MiB):
  char* ws = (char*)d_ws;
  unsigned short* wpsT  = (unsigned short*)(ws + 0x0000000);  // 1MB
  unsigned short* wptT  = (unsigned short*)(ws + 0x0100000);  // 1MB
  unsigned short* wqkvT = (unsigned short*)(ws + 0x0200000);  // 1.5MB
  unsigned short* wtrT  = (unsigned short*)(ws + 0x0380000);  // 1MB
  unsigned short* wsrT  = (unsigned short*)(ws + 0x0480000);  // 1MB
  unsigned short* cmb   = (unsigned short*)(ws + 0x0580000);  // 12.7MB
  unsigned short* xa    = (unsigned short*)(ws + 0x1300000);  // 47.2MB [46080][512]
  unsigned short* Sa    = (unsigned short*)(ws + 0x4000000);  // 94.4MB cast-A  (union
  unsigned short* qkvF  = (unsigned short*)(ws + 0x4000000);  //  w/ 141.6MB qkv)
  float* outb           = (float*)d_out;

  transpose_cast<<<2048, 256, 0, stream>>>(w_ps, wpsT, 1024, 512);
  transpose_cast<<<2048, 256, 0, stream>>>(w_pt, wptT, 1024, 512);
  transpose_cast<<<3072, 256, 0, stream>>>(w_qkv, wqkvT, 512, 1536);
  transpose_cast<<<2048, 256, 0, stream>>>(w_tr, wtrT, 512, 1024);
  transpose_cast<<<2048, 256, 0, stream>>>(w_sr, wsrT, 512, 1024);
  build_cmb<<<(NCLS * NHEADS * NTOK * NTOK + 255) / 256, 256, 0, stream>>>(rpb, mask0, mask1, cmb);

  // cast inputs to bf16: tpl -> Sa[0:9216), x -> Sa[9216:46080)
  cast_bf16<<<(TROWS * 1024 / 8 + 255) / 256, 256, 0, stream>>>(tpl, Sa, TROWS * 1024 / 8);
  cast_bf16<<<(SROWS * 1024 / 8 + 255) / 256, 256, 0, stream>>>(
      x, Sa + (size_t)TROWS * 1024, SROWS * 1024 / 8);

  // projection GEMM (merged template+search) -> xa bf16
  gemm_glds<0><<<dim3(360, 4), 256, 0, stream>>>(Sa, wptT, wpsT, b_pt, b_ps,
                                                 xa, TOTROWS, CDIM, 1024);
  // LayerNorm in place on xa
  ln_kernel<<<TOTROWS / 4, 256, 0, stream>>>(xa, g_pt, be_pt, g_ps, be_ps);

  // QKV GEMM (one dispatch) -> qkvF (overwrites dead Sa)
  gemm_glds<1><<<dim3(360, 12), 256, 0, stream>>>(xa, wqkvT, wqkvT, b_qkv, b_qkv,
                                                  qkvF, TOTROWS, 1536, CDIM);
  // fused attention (one dispatch) -> xa
  attn_kernel<<<NWIN * NHEADS, 576, 0, stream>>>(qkvF, cmb, xa);

  // output GEMM (merged template+search) -> d_out f32
  gemm_glds<2><<<dim3(360, 8), 256, 0, stream>>>(xa, wtrT, wsrT, b_tr, b_sr,
                                                 outb, TOTROWS, 1024, CDIM);
}

// Round 9
// 522.250 us; speedup vs baseline: 1.1932x; 1.0864x over previous
//
#include <hip/hip_runtime.h>

// MixingAttention on MI355X (gfx950) — ROUND 9.
// Attention rewrite: swapped QK^T (S^T in regs, q = lane&15), softmax with 2
// shuffles, P kept in registers (permuted-contract PV vs LDS V^T), no Ps LDS,
// one barrier. LDS 59KB -> 10.75KB.

using s16x8 = __attribute__((ext_vector_type(8))) short;   // 8 bf16
using f32x4 = __attribute__((ext_vector_type(4))) float;   // 4 f32 acc
typedef __attribute__((ext_vector_type(2))) unsigned u32x2;

#define NTOK 144
#define NHEADS 16
#define CDIM 512
#define TROWS 9216     // 64*144 template rows
#define SROWS 36864    // 256*144 search rows
#define TOTROWS 46080
#define NWIN 320
#define NCLS 20        // 4 (mask1) + 16 (mask0) mask classes

__device__ __forceinline__ unsigned short f2bf(float f) {
  unsigned u = __float_as_uint(f);
  u += 0x7fffu + ((u >> 16) & 1u);     // RNE
  return (unsigned short)(u >> 16);
}
__device__ __forceinline__ float bf2f(unsigned short u) {
  return __uint_as_float(((unsigned)u) << 16);
}
__device__ __forceinline__ s16x8 mk8(unsigned a, unsigned b, unsigned c, unsigned d) {
  union { unsigned u[4]; s16x8 v; } x;
  x.u[0] = a; x.u[1] = b; x.u[2] = c; x.u[3] = d;
  return x.v;
}

// async global->LDS, 16B per lane; lds base must be wave-uniform.
__device__ __forceinline__ void gld16(const unsigned short* g, short* l) {
  __builtin_amdgcn_global_load_lds(
      (const __attribute__((address_space(1))) unsigned int*)g,
      (__attribute__((address_space(3))) unsigned int*)l, 16, 0, 0);
}

// ---------------- prep kernels ----------------

__global__ void transpose_cast(const float* __restrict__ w,
                               unsigned short* __restrict__ wT, int Kd, int Nd) {
  int i = blockIdx.x * 256 + threadIdx.x;
  if (i >= Kd * Nd) return;
  int n = i / Kd, k = i % Kd;
  wT[i] = f2bf(w[(size_t)k * Nd + n]);
}

__global__ __launch_bounds__(256) void cast_bf16(const float* __restrict__ in,
                                                 unsigned short* __restrict__ out, int n8) {
  int i = blockIdx.x * 256 + threadIdx.x;
  if (i >= n8) return;
  const float4* p = (const float4*)in + (size_t)i * 2;
  float4 f0 = p[0], f1 = p[1];
  s16x8 o;
  o[0] = (short)f2bf(f0.x); o[1] = (short)f2bf(f0.y);
  o[2] = (short)f2bf(f0.z); o[3] = (short)f2bf(f0.w);
  o[4] = (short)f2bf(f1.x); o[5] = (short)f2bf(f1.y);
  o[6] = (short)f2bf(f1.z); o[7] = (short)f2bf(f1.w);
  *(s16x8*)&out[(size_t)i * 8] = o;
}

// cmb[cls][h][qi][kj] = rel-pos-bias(h,qi,kj) + mask(cls,qi,kj), bf16
__global__ void build_cmb(const float* __restrict__ rpb, const float* __restrict__ m0,
                          const float* __restrict__ m1, unsigned short* __restrict__ cmb) {
  int i = blockIdx.x * 256 + threadIdx.x;
  if (i >= NCLS * NHEADS * NTOK * NTOK) return;
  int cls = i / (NHEADS * NTOK * NTOK);
  int rem = i % (NHEADS * NTOK * NTOK);
  int h = rem / (NTOK * NTOK);
  int ij = rem % (NTOK * NTOK);
  int qi = ij / NTOK, kj = ij % NTOK;
  int dh = qi / 12 - kj / 12 + 11;
  int dw = qi % 12 - kj % 12 + 11;
  float bias = rpb[(dh * 23 + dw) * NHEADS + h];
  float mv = (cls < 4) ? m1[(size_t)cls * NTOK * NTOK + ij]
                       : m0[(size_t)(cls - 4) * NTOK * NTOK + ij];
  cmb[i] = f2bf(bias + mv);
}

// ---------------- m97-structure MFMA GEMM (global_load_lds staging) ----------
template<int EPI>
__global__ __launch_bounds__(256) void gemm_glds(
    const unsigned short* __restrict__ Ab,
    const unsigned short* __restrict__ BTt, const unsigned short* __restrict__ BTs,
    const float* __restrict__ biast, const float* __restrict__ biass,
    void* __restrict__ Cout, int M, int N, int K)
{
  __shared__ short As[128 * 32];
  __shared__ short Bs[128 * 32];
  const int t = threadIdx.x;
  const int lane = t & 63, wv = t >> 6, lg = lane >> 4, lc = lane & 15;
  const int bm = blockIdx.x * 128, bn = blockIdx.y * 128;
  const bool isT = bm < TROWS;
  const unsigned short* BT = isT ? BTt : BTs;
  const float* bias = isT ? biast : biass;

  const int srow = wv * 16 + (lane >> 2);
  const int scol = (lane & 3) * 8;
  const unsigned short* aSrc = Ab + (size_t)(bm + srow) * K + scol;
  const unsigned short* bSrc = BT + (size_t)(bn + srow) * K + scol;
  const size_t rowK64 = (size_t)64 * K;

  f32x4 acc[2][8] = {};

  for (int kt = 0; kt < K; kt += 32) {
    __syncthreads();
    gld16(aSrc + kt,          &As[wv * 512]);
    gld16(aSrc + kt + rowK64, &As[2048 + wv * 512]);
    gld16(bSrc + kt,          &Bs[wv * 512]);
    gld16(bSrc + kt + rowK64, &Bs[2048 + wv * 512]);
    __syncthreads();
    s16x8 a0 = *(const s16x8*)&As[(wv * 32 + lc) * 32 + lg * 8];
    s16x8 a1 = *(const s16x8*)&As[(wv * 32 + 16 + lc) * 32 + lg * 8];
#pragma unroll
    for (int nt = 0; nt < 8; nt++) {
      s16x8 bfr = *(const s16x8*)&Bs[(nt * 16 + lc) * 32 + lg * 8];
      acc[0][nt] = __builtin_amdgcn_mfma_f32_16x16x32_bf16(a0, bfr, acc[0][nt], 0, 0, 0);
      acc[1][nt] = __builtin_amdgcn_mfma_f32_16x16x32_bf16(a1, bfr, acc[1][nt], 0, 0, 0);
    }
  }

#pragma unroll
  for (int mt = 0; mt < 2; mt++) {
    const int rbase = bm + wv * 32 + mt * 16 + lg * 4;
#pragma unroll
    for (int nt = 0; nt < 8; nt++) {
      const int cg = bn + nt * 16 + lc;
#pragma unroll
      for (int r = 0; r < 4; r++) {
        const int rg = rbase + r;
        float val = acc[mt][nt][r] + bias[cg];
        if (EPI == 2) {
          ((float*)Cout)[(size_t)rg * N + cg] = val;
        } else {
          if (EPI == 1 && cg < 512) val *= 0.17677669529663687f;   // Q scale
          ((unsigned short*)Cout)[(size_t)rg * N + cg] = f2bf(val);
        }
      }
    }
  }
}

// ---------------- LayerNorm, in place, vectorized (wave per row) ----------------
__global__ __launch_bounds__(256) void ln_kernel(
    unsigned short* __restrict__ xa,
    const float* __restrict__ g_pt, const float* __restrict__ be_pt,
    const float* __restrict__ g_ps, const float* __restrict__ be_ps)
{
  const int row = blockIdx.x * 4 + (threadIdx.x >> 6);
  const int lane = threadIdx.x & 63;
  const bool isT = row < TROWS;
  const float* gg = isT ? g_pt : g_ps;
  const float* be = isT ? be_pt : be_ps;
  unsigned short* p = xa + (size_t)row * CDIM;
  const int c0 = lane * 8;

  s16x8 v8 = *(const s16x8*)&p[c0];
  float f[8];
  float s = 0.f, s2 = 0.f;
#pragma unroll
  for (int i = 0; i < 8; i++) {
    float xv = bf2f((unsigned short)v8[i]);
    f[i] = xv; s += xv; s2 += xv * xv;
  }
#pragma unroll
  for (int d = 1; d < 64; d <<= 1) { s += __shfl_xor(s, d); s2 += __shfl_xor(s2, d); }
  float mu = s * (1.f / CDIM);
  float var = s2 * (1.f / CDIM) - mu * mu;
  float rs = rsqrtf(var + 1e-5f);

  float4 g0 = *(const float4*)&gg[c0], g1 = *(const float4*)&gg[c0 + 4];
  float4 e0 = *(const float4*)&be[c0], e1 = *(const float4*)&be[c0 + 4];
  float gv[8] = {g0.x, g0.y, g0.z, g0.w, g1.x, g1.y, g1.z, g1.w};
  float ev[8] = {e0.x, e0.y, e0.z, e0.w, e1.x, e1.y, e1.z, e1.w};
  s16x8 o;
#pragma unroll
  for (int i = 0; i < 8; i++)
    o[i] = (short)f2bf((f[i] - mu) * rs * gv[i] + ev[i]);
  *(s16x8*)&p[c0] = o;
}

// ---------------- fused attention, swapped-operand, one block per (w,h) ------
// qkv: [TOTROWS][1536] bf16 (q | k | v, each 16 heads x 32 dims).
// S^T = mfma(K_frag, Q_frag): lane holds q = wv*16 + (lane&15),
// keys n = 16*nt + (lane>>4)*4 + r. P stays in registers; PV feeds P as the
// B-operand with a per-lane permuted contract index and reads V^T (LDS) at
// matching offsets. One barrier total.
__global__ __launch_bounds__(576) void attn_kernel(
    const unsigned short* __restrict__ qkv, const unsigned short* __restrict__ cmb,
    unsigned short* __restrict__ outp)
{
  __shared__ short VT[32 * 168];    // VT[d][key], keys 144..159 zeroed
  const int w = blockIdx.x >> 4, h = blockIdx.x & 15;
  const int t = threadIdx.x;
  const unsigned short* qb = qkv + (size_t)w * NTOK * 1536;
  const int hq = h * 32;

  {  // stage V transposed
    const int n = t >> 2, d0 = (t & 3) * 8;
    s16x8 vv = *(const s16x8*)&qb[(size_t)n * 1536 + 1024 + hq + d0];
#pragma unroll
    for (int i = 0; i < 8; i++) VT[(d0 + i) * 168 + n] = vv[i];
  }
  if (t < 512) VT[(t >> 4) * 168 + 144 + (t & 15)] = 0;
  __syncthreads();

  const int lane = t & 63, wv = t >> 6, lg = lane >> 4, lc = lane & 15;
  const int q = wv * 16 + lc;           // this lane's query row (window-local)
  const f32x4 zero = {0.f, 0.f, 0.f, 0.f};

  // Q fragment (B-operand): Q[q][lg*8 .. +7]
  const s16x8 qf = *(const s16x8*)&qb[(size_t)q * 1536 + hq + lg * 8];

  // bias+mask row for this q (9 x 8B loads, keys 16nt+lg*4..+3)
  const int cls = (w < 64) ? (w & 3) : 4 + ((w - 64) & 15);
  const unsigned short* cm =
      cmb + ((size_t)cls * NHEADS + h) * (NTOK * NTOK) + (size_t)q * NTOK;
  uint2 cmr[9];
#pragma unroll
  for (int nt = 0; nt < 9; nt++)
    cmr[nt] = *(const uint2*)&cm[nt * 16 + lg * 4];

  // S^T: 9 MFMAs, A = K frags, B = Q frag
  f32x4 accS[9];
#pragma unroll
  for (int nt = 0; nt < 9; nt++) {
    s16x8 kf = *(const s16x8*)&qb[(size_t)(nt * 16 + lc) * 1536 + 512 + hq + lg * 8];
    accS[nt] = __builtin_amdgcn_mfma_f32_16x16x32_bf16(kf, qf, zero, 0, 0, 0);
  }

  // add bias+mask, row-max (36 local values + 2 shuffles)
  float mx = -1e30f;
#pragma unroll
  for (int nt = 0; nt < 9; nt++) {
    accS[nt][0] += bf2f((unsigned short)(cmr[nt].x & 0xffff));
    accS[nt][1] += bf2f((unsigned short)(cmr[nt].x >> 16));
    accS[nt][2] += bf2f((unsigned short)(cmr[nt].y & 0xffff));
    accS[nt][3] += bf2f((unsigned short)(cmr[nt].y >> 16));
#pragma unroll
    for (int r = 0; r < 4; r++) mx = fmaxf(mx, accS[nt][r]);
  }
  mx = fmaxf(mx, __shfl_xor(mx, 16));
  mx = fmaxf(mx, __shfl_xor(mx, 32));

  // exp + sum (normalization deferred to O)
  float sum = 0.f;
#pragma unroll
  for (int nt = 0; nt < 9; nt++)
#pragma unroll
    for (int r = 0; r < 4; r++) {
      float e = __expf(accS[nt][r] - mx);
      accS[nt][r] = e;
      sum += e;
    }
  sum += __shfl_xor(sum, 16);
  sum += __shfl_xor(sum, 32);
  const float inv = 1.f / sum;

  // pack P to bf16 dwords (lane-local)
  unsigned pk0[9], pk1[9];
#pragma unroll
  for (int nt = 0; nt < 9; nt++) {
    pk0[nt] = (unsigned)f2bf(accS[nt][0]) | ((unsigned)f2bf(accS[nt][1]) << 16);
    pk1[nt] = (unsigned)f2bf(accS[nt][2]) | ((unsigned)f2bf(accS[nt][3]) << 16);
  }

  // O^T = V^T · P^T with per-lane permuted contract index:
  // B elems 0..3 = keys 32kk+lg*4..+3 (tile 2kk), 4..7 = +16 (tile 2kk+1);
  // A (V^T row d=dt*16+lc) read at the same key offsets.
#pragma unroll
  for (int dt = 0; dt < 2; dt++) {
    const short* vbase = &VT[(dt * 16 + lc) * 168];
    f32x4 accO = zero;
#pragma unroll
    for (int kk = 0; kk < 4; kk++) {
      u32x2 A0 = *(const u32x2*)&vbase[32 * kk + lg * 4];
      u32x2 A1 = *(const u32x2*)&vbase[32 * kk + 16 + lg * 4];
      s16x8 a = mk8(A0[0], A0[1], A1[0], A1[1]);
      s16x8 b = mk8(pk0[2 * kk], pk1[2 * kk], pk0[2 * kk + 1], pk1[2 * kk + 1]);
      accO = __builtin_amdgcn_mfma_f32_16x16x32_bf16(a, b, accO, 0, 0, 0);
    }
    {  // tail: keys 128..143 (tile 8) + zeros
      u32x2 A0 = *(const u32x2*)&vbase[128 + lg * 4];
      s16x8 a = mk8(A0[0], A0[1], 0u, 0u);
      s16x8 b = mk8(pk0[8], pk1[8], 0u, 0u);
      accO = __builtin_amdgcn_mfma_f32_16x16x32_bf16(a, b, accO, 0, 0, 0);
    }
    // store 4 consecutive bf16 (cols h*32 + dt*16 + lg*4 ..), scaled by inv
    unsigned o0 = (unsigned)f2bf(accO[0] * inv) | ((unsigned)f2bf(accO[1] * inv) << 16);
    unsigned o1 = (unsigned)f2bf(accO[2] * inv) | ((unsigned)f2bf(accO[3] * inv) << 16);
    uint2 st; st.x = o0; st.y = o1;
    *(uint2*)&outp[(size_t)(w * NTOK + q) * CDIM + hq + dt * 16 + lg * 4] = st;
  }
}

// ---------------- launch ----------------
extern "C" void kernel_launch(void* const* d_in, const int* in_sizes, int n_in,
                              void* d_out, int out_size, void* d_ws, size_t ws_size,
                              hipStream_t stream)
{
  const float* x     = (const float*)d_in[0];
  const float* tpl   = (const float*)d_in[1];
  const float* mask0 = (const float*)d_in[2];
  const float* mask1 = (const float*)d_in[3];
  const float* rpb   = (const float*)d_in[8];
  const float* w_ps  = (const float*)d_in[9];
  const float* b_ps  = (const float*)d_in[10];
  const float* g_ps  = (const float*)d_in[11];
  const float* be_ps = (const float*)d_in[12];
  const float* w_pt  = (const float*)d_in[13];
  const float* b_pt  = (const float*)d_in[14];
  const float* g_pt  = (const float*)d_in[15];
  const float* be_pt = (const float*)d_in[16];
  const float* w_qkv = (const float*)d_in[17];
  const float* b_qkv = (const float*)d_in[18];
  const float* w_tr  = (const float*)d_in[19];
  const float* b_tr  = (const float*)d_in[20];
  const float* w_sr  = (const float*)d_in[21];
  const float* b_sr  = (const float*)d_in[22];

  // ws layout (~208MB of 720MiB):
  char* ws = (char*)d_ws;
  unsigned short* wpsT  = (unsigned short*)(ws + 0x0000000);  // 1MB
  unsigned short* wptT  = (unsigned short*)(ws + 0x0100000);  // 1MB
  unsigned short* wqkvT = (unsigned short*)(ws + 0x0200000);  // 1.5MB
  unsigned short* wtrT  = (unsigned short*)(ws + 0x0380000);  // 1MB
  unsigned short* wsrT  = (unsigned short*)(ws + 0x0480000);  // 1MB
  unsigned short* cmb   = (unsigned short*)(ws + 0x0580000);  // 12.7MB
  unsigned short* xa    = (unsigned short*)(ws + 0x1300000);  // 47.2MB [46080][512]
  unsigned short* Sa    = (unsigned short*)(ws + 0x4000000);  // 94.4MB cast-A  (union
  unsigned short* qkvF  = (unsigned short*)(ws + 0x4000000);  //  w/ 141.6MB qkv)
  float* outb           = (float*)d_out;

  transpose_cast<<<2048, 256, 0, stream>>>(w_ps, wpsT, 1024, 512);
  transpose_cast<<<2048, 256, 0, stream>>>(w_pt, wptT, 1024, 512);
  transpose_cast<<<3072, 256, 0, stream>>>(w_qkv, wqkvT, 512, 1536);
  transpose_cast<<<2048, 256, 0, stream>>>(w_tr, wtrT, 512, 1024);
  transpose_cast<<<2048, 256, 0, stream>>>(w_sr, wsrT, 512, 1024);
  build_cmb<<<(NCLS * NHEADS * NTOK * NTOK + 255) / 256, 256, 0, stream>>>(rpb, mask0, mask1, cmb);

  // cast inputs to bf16: tpl -> Sa[0:9216), x -> Sa[9216:46080)
  cast_bf16<<<(TROWS * 1024 / 8 + 255) / 256, 256, 0, stream>>>(tpl, Sa, TROWS * 1024 / 8);
  cast_bf16<<<(SROWS * 1024 / 8 + 255) / 256, 256, 0, stream>>>(
      x, Sa + (size_t)TROWS * 1024, SROWS * 1024 / 8);

  // projection GEMM (merged template+search) -> xa bf16
  gemm_glds<0><<<dim3(360, 4), 256, 0, stream>>>(Sa, wptT, wpsT, b_pt, b_ps,
                                                 xa, TOTROWS, CDIM, 1024);
  // LayerNorm in place on xa
  ln_kernel<<<TOTROWS / 4, 256, 0, stream>>>(xa, g_pt, be_pt, g_ps, be_ps);

  // QKV GEMM (one dispatch) -> qkvF (overwrites dead Sa)
  gemm_glds<1><<<dim3(360, 12), 256, 0, stream>>>(xa, wqkvT, wqkvT, b_qkv, b_qkv,
                                                  qkvF, TOTROWS, 1536, CDIM);
  // fused attention (one dispatch) -> xa
  attn_kernel<<<NWIN * NHEADS, 576, 0, stream>>>(qkvF, cmb, xa);

  // output GEMM (merged template+search) -> d_out f32
  gemm_glds<2><<<dim3(360, 8), 256, 0, stream>>>(xa, wtrT, wsrT, b_tr, b_sr,
                                                 outb, TOTROWS, 1024, CDIM);
}

// Round 10
// 505.477 us; speedup vs baseline: 1.2328x; 1.0332x over previous
//
#include <hip/hip_runtime.h>

// MixingAttention on MI355X (gfx950) — ROUND 10.
// GEMM core upgrade: BK=64 (half the barriers), T2 XOR-swizzle applied
// both-sides (pre-swizzled global src + swizzled ds_read col; LDS dest
// stays linear for global_load_lds), grid swapped so N varies fastest
// (A-panel reuse runs concurrently across XCDs).

using s16x8 = __attribute__((ext_vector_type(8))) short;   // 8 bf16
using f32x4 = __attribute__((ext_vector_type(4))) float;   // 4 f32 acc
typedef __attribute__((ext_vector_type(2))) unsigned u32x2;

#define NTOK 144
#define NHEADS 16
#define CDIM 512
#define TROWS 9216     // 64*144 template rows
#define SROWS 36864    // 256*144 search rows
#define TOTROWS 46080
#define NWIN 320
#define NCLS 20        // 4 (mask1) + 16 (mask0) mask classes

__device__ __forceinline__ unsigned short f2bf(float f) {
  unsigned u = __float_as_uint(f);
  u += 0x7fffu + ((u >> 16) & 1u);     // RNE
  return (unsigned short)(u >> 16);
}
__device__ __forceinline__ float bf2f(unsigned short u) {
  return __uint_as_float(((unsigned)u) << 16);
}
__device__ __forceinline__ s16x8 mk8(unsigned a, unsigned b, unsigned c, unsigned d) {
  union { unsigned u[4]; s16x8 v; } x;
  x.u[0] = a; x.u[1] = b; x.u[2] = c; x.u[3] = d;
  return x.v;
}

// async global->LDS, 16B per lane; lds base must be wave-uniform.
__device__ __forceinline__ void gld16(const unsigned short* g, short* l) {
  __builtin_amdgcn_global_load_lds(
      (const __attribute__((address_space(1))) unsigned int*)g,
      (__attribute__((address_space(3))) unsigned int*)l, 16, 0, 0);
}

// ---------------- prep kernels ----------------

__global__ void transpose_cast(const float* __restrict__ w,
                               unsigned short* __restrict__ wT, int Kd, int Nd) {
  int i = blockIdx.x * 256 + threadIdx.x;
  if (i >= Kd * Nd) return;
  int n = i / Kd, k = i % Kd;
  wT[i] = f2bf(w[(size_t)k * Nd + n]);
}

__global__ __launch_bounds__(256) void cast_bf16(const float* __restrict__ in,
                                                 unsigned short* __restrict__ out, int n8) {
  int i = blockIdx.x * 256 + threadIdx.x;
  if (i >= n8) return;
  const float4* p = (const float4*)in + (size_t)i * 2;
  float4 f0 = p[0], f1 = p[1];
  s16x8 o;
  o[0] = (short)f2bf(f0.x); o[1] = (short)f2bf(f0.y);
  o[2] = (short)f2bf(f0.z); o[3] = (short)f2bf(f0.w);
  o[4] = (short)f2bf(f1.x); o[5] = (short)f2bf(f1.y);
  o[6] = (short)f2bf(f1.z); o[7] = (short)f2bf(f1.w);
  *(s16x8*)&out[(size_t)i * 8] = o;
}

// cmb[cls][h][qi][kj] = rel-pos-bias(h,qi,kj) + mask(cls,qi,kj), bf16
__global__ void build_cmb(const float* __restrict__ rpb, const float* __restrict__ m0,
                          const float* __restrict__ m1, unsigned short* __restrict__ cmb) {
  int i = blockIdx.x * 256 + threadIdx.x;
  if (i >= NCLS * NHEADS * NTOK * NTOK) return;
  int cls = i / (NHEADS * NTOK * NTOK);
  int rem = i % (NHEADS * NTOK * NTOK);
  int h = rem / (NTOK * NTOK);
  int ij = rem % (NTOK * NTOK);
  int qi = ij / NTOK, kj = ij % NTOK;
  int dh = qi / 12 - kj / 12 + 11;
  int dw = qi % 12 - kj % 12 + 11;
  float bias = rpb[(dh * 23 + dw) * NHEADS + h];
  float mv = (cls < 4) ? m1[(size_t)cls * NTOK * NTOK + ij]
                       : m0[(size_t)(cls - 4) * NTOK * NTOK + ij];
  cmb[i] = f2bf(bias + mv);
}

// ---------------- MFMA GEMM: BK=64, XOR-swizzled, glds staging ----------
// C(M,N) = A(M,K) @ B(K,N); per-row-block select: rows < TROWS use BTt/biast.
// LDS layout: linear [128][64] shorts; LDS slot (row, grp p) holds global
// col-group p ^ (row&7)  (pre-swizzled global source; swizzled read).
// EPI 0: +bias, bf16.  EPI 1: +bias, Q-scale cols<512, bf16.  EPI 2: +bias, f32.
template<int EPI>
__global__ __launch_bounds__(256) void gemm_glds(
    const unsigned short* __restrict__ Ab,
    const unsigned short* __restrict__ BTt, const unsigned short* __restrict__ BTs,
    const float* __restrict__ biast, const float* __restrict__ biass,
    void* __restrict__ Cout, int M, int N, int K)
{
  __shared__ short As[128 * 64];   // 16KB
  __shared__ short Bs[128 * 64];   // 16KB
  const int t = threadIdx.x;
  const int lane = t & 63, wv = t >> 6, lg = lane >> 4, lc = lane & 15;
  const int bn = blockIdx.x * 128, bm = blockIdx.y * 128;   // N fastest
  const bool isT = bm < TROWS;
  const unsigned short* BT = isT ? BTt : BTs;
  const float* bias = isT ? biast : biass;

  // staging: instr i of wave wv covers rows 32*wv+8*i..+7 (j = wv*4+i);
  // lane l -> row 32wv+8i+(l>>3), global col-group (l&7)^((l>>3)&7).
  const int srow = 32 * wv + (lane >> 3);
  const int scol = (((lane & 7) ^ ((lane >> 3) & 7))) * 8;
  const unsigned short* aSrc = Ab + (size_t)(bm + srow) * K + scol;
  const unsigned short* bSrc = BT + (size_t)(bn + srow) * K + scol;
  const size_t rowK8 = (size_t)8 * K;

  f32x4 acc[2][8] = {};

  for (int kt = 0; kt < K; kt += 64) {
    __syncthreads();
#pragma unroll
    for (int i = 0; i < 4; i++) {
      gld16(aSrc + kt + i * rowK8, &As[(wv * 4 + i) * 512]);
      gld16(bSrc + kt + i * rowK8, &Bs[(wv * 4 + i) * 512]);
    }
    __syncthreads();
#pragma unroll
    for (int kk = 0; kk < 2; kk++) {
      // all fragment rows == lc (mod 8) -> uniform per-lane swizzled col
      const int csw = 8 * ((4 * kk + lg) ^ (lc & 7));
      const int r0 = wv * 32 + lc, r1 = r0 + 16;
      s16x8 a0 = *(const s16x8*)&As[r0 * 64 + csw];
      s16x8 a1 = *(const s16x8*)&As[r1 * 64 + csw];
#pragma unroll
      for (int nt = 0; nt < 8; nt++) {
        s16x8 bfr = *(const s16x8*)&Bs[(nt * 16 + lc) * 64 + csw];
        acc[0][nt] = __builtin_amdgcn_mfma_f32_16x16x32_bf16(a0, bfr, acc[0][nt], 0, 0, 0);
        acc[1][nt] = __builtin_amdgcn_mfma_f32_16x16x32_bf16(a1, bfr, acc[1][nt], 0, 0, 0);
      }
    }
  }

#pragma unroll
  for (int mt = 0; mt < 2; mt++) {
    const int rbase = bm + wv * 32 + mt * 16 + lg * 4;
#pragma unroll
    for (int nt = 0; nt < 8; nt++) {
      const int cg = bn + nt * 16 + lc;
#pragma unroll
      for (int r = 0; r < 4; r++) {
        const int rg = rbase + r;
        float val = acc[mt][nt][r] + bias[cg];
        if (EPI == 2) {
          ((float*)Cout)[(size_t)rg * N + cg] = val;
        } else {
          if (EPI == 1 && cg < 512) val *= 0.17677669529663687f;   // Q scale
          ((unsigned short*)Cout)[(size_t)rg * N + cg] = f2bf(val);
        }
      }
    }
  }
}

// ---------------- LayerNorm, in place, vectorized (wave per row) ----------------
__global__ __launch_bounds__(256) void ln_kernel(
    unsigned short* __restrict__ xa,
    const float* __restrict__ g_pt, const float* __restrict__ be_pt,
    const float* __restrict__ g_ps, const float* __restrict__ be_ps)
{
  const int row = blockIdx.x * 4 + (threadIdx.x >> 6);
  const int lane = threadIdx.x & 63;
  const bool isT = row < TROWS;
  const float* gg = isT ? g_pt : g_ps;
  const float* be = isT ? be_pt : be_ps;
  unsigned short* p = xa + (size_t)row * CDIM;
  const int c0 = lane * 8;

  s16x8 v8 = *(const s16x8*)&p[c0];
  float f[8];
  float s = 0.f, s2 = 0.f;
#pragma unroll
  for (int i = 0; i < 8; i++) {
    float xv = bf2f((unsigned short)v8[i]);
    f[i] = xv; s += xv; s2 += xv * xv;
  }
#pragma unroll
  for (int d = 1; d < 64; d <<= 1) { s += __shfl_xor(s, d); s2 += __shfl_xor(s2, d); }
  float mu = s * (1.f / CDIM);
  float var = s2 * (1.f / CDIM) - mu * mu;
  float rs = rsqrtf(var + 1e-5f);

  float4 g0 = *(const float4*)&gg[c0], g1 = *(const float4*)&gg[c0 + 4];
  float4 e0 = *(const float4*)&be[c0], e1 = *(const float4*)&be[c0 + 4];
  float gv[8] = {g0.x, g0.y, g0.z, g0.w, g1.x, g1.y, g1.z, g1.w};
  float ev[8] = {e0.x, e0.y, e0.z, e0.w, e1.x, e1.y, e1.z, e1.w};
  s16x8 o;
#pragma unroll
  for (int i = 0; i < 8; i++)
    o[i] = (short)f2bf((f[i] - mu) * rs * gv[i] + ev[i]);
  *(s16x8*)&p[c0] = o;
}

// ---------------- fused attention, swapped-operand, one block per (w,h) ------
__global__ __launch_bounds__(576) void attn_kernel(
    const unsigned short* __restrict__ qkv, const unsigned short* __restrict__ cmb,
    unsigned short* __restrict__ outp)
{
  __shared__ short VT[32 * 168];    // VT[d][key], keys 144..159 zeroed
  const int w = blockIdx.x >> 4, h = blockIdx.x & 15;
  const int t = threadIdx.x;
  const unsigned short* qb = qkv + (size_t)w * NTOK * 1536;
  const int hq = h * 32;

  {  // stage V transposed
    const int n = t >> 2, d0 = (t & 3) * 8;
    s16x8 vv = *(const s16x8*)&qb[(size_t)n * 1536 + 1024 + hq + d0];
#pragma unroll
    for (int i = 0; i < 8; i++) VT[(d0 + i) * 168 + n] = vv[i];
  }
  if (t < 512) VT[(t >> 4) * 168 + 144 + (t & 15)] = 0;
  __syncthreads();

  const int lane = t & 63, wv = t >> 6, lg = lane >> 4, lc = lane & 15;
  const int q = wv * 16 + lc;           // this lane's query row (window-local)
  const f32x4 zero = {0.f, 0.f, 0.f, 0.f};

  // Q fragment (B-operand): Q[q][lg*8 .. +7]
  const s16x8 qf = *(const s16x8*)&qb[(size_t)q * 1536 + hq + lg * 8];

  // bias+mask row for this q (9 x 8B loads, keys 16nt+lg*4..+3)
  const int cls = (w < 64) ? (w & 3) : 4 + ((w - 64) & 15);
  const unsigned short* cm =
      cmb + ((size_t)cls * NHEADS + h) * (NTOK * NTOK) + (size_t)q * NTOK;
  uint2 cmr[9];
#pragma unroll
  for (int nt = 0; nt < 9; nt++)
    cmr[nt] = *(const uint2*)&cm[nt * 16 + lg * 4];

  // S^T: 9 MFMAs, A = K frags, B = Q frag
  f32x4 accS[9];
#pragma unroll
  for (int nt = 0; nt < 9; nt++) {
    s16x8 kf = *(const s16x8*)&qb[(size_t)(nt * 16 + lc) * 1536 + 512 + hq + lg * 8];
    accS[nt] = __builtin_amdgcn_mfma_f32_16x16x32_bf16(kf, qf, zero, 0, 0, 0);
  }

  // add bias+mask, row-max (36 local values + 2 shuffles)
  float mx = -1e30f;
#pragma unroll
  for (int nt = 0; nt < 9; nt++) {
    accS[nt][0] += bf2f((unsigned short)(cmr[nt].x & 0xffff));
    accS[nt][1] += bf2f((unsigned short)(cmr[nt].x >> 16));
    accS[nt][2] += bf2f((unsigned short)(cmr[nt].y & 0xffff));
    accS[nt][3] += bf2f((unsigned short)(cmr[nt].y >> 16));
#pragma unroll
    for (int r = 0; r < 4; r++) mx = fmaxf(mx, accS[nt][r]);
  }
  mx = fmaxf(mx, __shfl_xor(mx, 16));
  mx = fmaxf(mx, __shfl_xor(mx, 32));

  // exp + sum (normalization deferred to O)
  float sum = 0.f;
#pragma unroll
  for (int nt = 0; nt < 9; nt++)
#pragma unroll
    for (int r = 0; r < 4; r++) {
      float e = __expf(accS[nt][r] - mx);
      accS[nt][r] = e;
      sum += e;
    }
  sum += __shfl_xor(sum, 16);
  sum += __shfl_xor(sum, 32);
  const float inv = 1.f / sum;

  // pack P to bf16 dwords (lane-local)
  unsigned pk0[9], pk1[9];
#pragma unroll
  for (int nt = 0; nt < 9; nt++) {
    pk0[nt] = (unsigned)f2bf(accS[nt][0]) | ((unsigned)f2bf(accS[nt][1]) << 16);
    pk1[nt] = (unsigned)f2bf(accS[nt][2]) | ((unsigned)f2bf(accS[nt][3]) << 16);
  }

  // O^T = V^T · P^T with per-lane permuted contract index
#pragma unroll
  for (int dt = 0; dt < 2; dt++) {
    const short* vbase = &VT[(dt * 16 + lc) * 168];
    f32x4 accO = zero;
#pragma unroll
    for (int kk = 0; kk < 4; kk++) {
      u32x2 A0 = *(const u32x2*)&vbase[32 * kk + lg * 4];
      u32x2 A1 = *(const u32x2*)&vbase[32 * kk + 16 + lg * 4];
      s16x8 a = mk8(A0[0], A0[1], A1[0], A1[1]);
      s16x8 b = mk8(pk0[2 * kk], pk1[2 * kk], pk0[2 * kk + 1], pk1[2 * kk + 1]);
      accO = __builtin_amdgcn_mfma_f32_16x16x32_bf16(a, b, accO, 0, 0, 0);
    }
    {  // tail: keys 128..143 (tile 8) + zeros
      u32x2 A0 = *(const u32x2*)&vbase[128 + lg * 4];
      s16x8 a = mk8(A0[0], A0[1], 0u, 0u);
      s16x8 b = mk8(pk0[8], pk1[8], 0u, 0u);
      accO = __builtin_amdgcn_mfma_f32_16x16x32_bf16(a, b, accO, 0, 0, 0);
    }
    unsigned o0 = (unsigned)f2bf(accO[0] * inv) | ((unsigned)f2bf(accO[1] * inv) << 16);
    unsigned o1 = (unsigned)f2bf(accO[2] * inv) | ((unsigned)f2bf(accO[3] * inv) << 16);
    uint2 st; st.x = o0; st.y = o1;
    *(uint2*)&outp[(size_t)(w * NTOK + q) * CDIM + hq + dt * 16 + lg * 4] = st;
  }
}

// ---------------- launch ----------------
extern "C" void kernel_launch(void* const* d_in, const int* in_sizes, int n_in,
                              void* d_out, int out_size, void* d_ws, size_t ws_size,
                              hipStream_t stream)
{
  const float* x     = (const float*)d_in[0];
  const float* tpl   = (const float*)d_in[1];
  const float* mask0 = (const float*)d_in[2];
  const float* mask1 = (const float*)d_in[3];
  const float* rpb   = (const float*)d_in[8];
  const float* w_ps  = (const float*)d_in[9];
  const float* b_ps  = (const float*)d_in[10];
  const float* g_ps  = (const float*)d_in[11];
  const float* be_ps = (const float*)d_in[12];
  const float* w_pt  = (const float*)d_in[13];
  const float* b_pt  = (const float*)d_in[14];
  const float* g_pt  = (const float*)d_in[15];
  const float* be_pt = (const float*)d_in[16];
  const float* w_qkv = (const float*)d_in[17];
  const float* b_qkv = (const float*)d_in[18];
  const float* w_tr  = (const float*)d_in[19];
  const float* b_tr  = (const float*)d_in[20];
  const float* w_sr  = (const float*)d_in[21];
  const float* b_sr  = (const float*)d_in[22];

  // ws layout (~208MB of 720MiB):
  char* ws = (char*)d_ws;
  unsigned short* wpsT  = (unsigned short*)(ws + 0x0000000);  // 1MB
  unsigned short* wptT  = (unsigned short*)(ws + 0x0100000);  // 1MB
  unsigned short* wqkvT = (unsigned short*)(ws + 0x0200000);  // 1.5MB
  unsigned short* wtrT  = (unsigned short*)(ws + 0x0380000);  // 1MB
  unsigned short* wsrT  = (unsigned short*)(ws + 0x0480000);  // 1MB
  unsigned short* cmb   = (unsigned short*)(ws + 0x0580000);  // 12.7MB
  unsigned short* xa    = (unsigned short*)(ws + 0x1300000);  // 47.2MB [46080][512]
  unsigned short* Sa    = (unsigned short*)(ws + 0x4000000);  // 94.4MB cast-A  (union
  unsigned short* qkvF  = (unsigned short*)(ws + 0x4000000);  //  w/ 141.6MB qkv)
  float* outb           = (float*)d_out;

  transpose_cast<<<2048, 256, 0, stream>>>(w_ps, wpsT, 1024, 512);
  transpose_cast<<<2048, 256, 0, stream>>>(w_pt, wptT, 1024, 512);
  transpose_cast<<<3072, 256, 0, stream>>>(w_qkv, wqkvT, 512, 1536);
  transpose_cast<<<2048, 256, 0, stream>>>(w_tr, wtrT, 512, 1024);
  transpose_cast<<<2048, 256, 0, stream>>>(w_sr, wsrT, 512, 1024);
  build_cmb<<<(NCLS * NHEADS * NTOK * NTOK + 255) / 256, 256, 0, stream>>>(rpb, mask0, mask1, cmb);

  // cast inputs to bf16: tpl -> Sa[0:9216), x -> Sa[9216:46080)
  cast_bf16<<<(TROWS * 1024 / 8 + 255) / 256, 256, 0, stream>>>(tpl, Sa, TROWS * 1024 / 8);
  cast_bf16<<<(SROWS * 1024 / 8 + 255) / 256, 256, 0, stream>>>(
      x, Sa + (size_t)TROWS * 1024, SROWS * 1024 / 8);

  // projection GEMM (merged template+search) -> xa bf16   [grid: N fastest]
  gemm_glds<0><<<dim3(4, 360), 256, 0, stream>>>(Sa, wptT, wpsT, b_pt, b_ps,
                                                 xa, TOTROWS, CDIM, 1024);
  // LayerNorm in place on xa
  ln_kernel<<<TOTROWS / 4, 256, 0, stream>>>(xa, g_pt, be_pt, g_ps, be_ps);

  // QKV GEMM (one dispatch) -> qkvF (overwrites dead Sa)
  gemm_glds<1><<<dim3(12, 360), 256, 0, stream>>>(xa, wqkvT, wqkvT, b_qkv, b_qkv,
                                                  qkvF, TOTROWS, 1536, CDIM);
  // fused attention (one dispatch) -> xa
  attn_kernel<<<NWIN * NHEADS, 576, 0, stream>>>(qkvF, cmb, xa);

  // output GEMM (merged template+search) -> d_out f32
  gemm_glds<2><<<dim3(8, 360), 256, 0, stream>>>(xa, wtrT, wsrT, b_tr, b_sr,
                                                 outb, TOTROWS, 1024, CDIM);
}